// Round 6
// baseline (260.200 us; speedup 1.0000x reference)
//
#include <hip/hip_runtime.h>

// out[b,s,d] = alpha*sum_{j=1..P} beta^{j-1} x[b,s-j,d] + pf[d] + pb[((s>>5)-d)&31]
//
// NO-NT + PARALLEL WINDOW GATHER. Round table R1/R4/R5 = 80/85/87 us at 16..32
// waves/CU and 265..336 MB: a wall independent of TLP and bytes. All rounds used
// nontemporal stores; reconstructed store rates sit at ~1.5-2.5 TB/s while the
// harness's fillBuffer writes 6.7 TB/s with PLAIN stores on the same buffer.
// Theory: nt bypasses L2 write-combining -> shallow store queue -> ~2.5 TB/s cap;
// a 1:1 read:write kernel is store-capped there (R0's 5.3 TB/s system didn't hit
// it only because its 3x redundant reads set the pace). So: plain stores.
// Also: the decay window is FINITE (P = 128 = 8 chunks), so the block-wide serial
// scan was never needed: carry into chunk c is y0 = alpha * sum_{k=1..8}
// beta^{16(k-1)} A_{c-k} -- each thread Horner-gathers its own 8 chunk sums from
// sA after ONE barrier. Serial section, sC, and the second barrier deleted.
// sA columns XOR-swizzled by (row>>3)&7 so the stride-8-row gather is
// bank-conflict-free. 4 pass-B loads pre-issued before the raw barrier
// (lgkmcnt-only wait, R2/R3-proven) so stores start immediately after it.
// Pass-B recurrence and FMA order identical to R0..R5 (absmax 0.03125 lineage);
// y0's Horner is the same windowed sum the scan produced (rounding-level diff).

typedef float f32x4 __attribute__((ext_vector_type(4)));

constexpr int S    = 1024;
constexpr int D    = 32;
constexpr int CL   = 16;              // 16-runs stay inside one 32-block => s>>5 const
constexpr int NCH  = S / CL;          // 64 chunks
constexpr int LAG  = 8;               // P / CL
constexpr int NTHR = NCH * (D / 4);   // 512 threads = 8 waves

__global__ __launch_bounds__(NTHR, 8)   // VGPR<=64 => 4 blocks/CU = 32 waves
void attn_pred_kernel(const float* __restrict__ x,
                      const float* __restrict__ alpha_p,
                      const float* __restrict__ beta_p,
                      const float* __restrict__ pos_fwd,
                      const float* __restrict__ pos_bwd,
                      const int*   __restrict__ past_p,
                      float* __restrict__ out)
{
    __shared__ f32x4 sA[NCH][D / 4];  // 4 KiB: pure chunk sums (cols XOR-swizzled)

    const int tid  = threadIdx.x;
    const int b    = blockIdx.x;
    const int lane = tid & 63;
    const int wv   = tid >> 6;        // wave 0..7
    const int g    = lane >> 3;       // lag-group 0..7 within wave
    const int dg   = lane & 7;        // float4 group over d
    const int c    = g * 8 + wv;      // chunk 0..63; chunk c-LAG == lane-8, same wave
    const int s0   = c * CL;

    const float alpha = alpha_p[0];
    const float beta  = beta_p[0];
    const int   P     = past_p[0];    // 128

    // beta^P by squaring (double), beta^CL by 4 squarings
    double bb = (double)beta, bpd = 1.0;
    for (int e = P; e; e >>= 1) { if (e & 1) bpd *= bb; bb *= bb; }
    const float bP = (float)bpd;
    double b16 = (double)beta;
    for (int i = 0; i < 4; ++i) b16 *= b16;
    const float bCL = (float)b16;     // beta^16
    const float aP  = alpha * bP;     // alpha*beta^P
    const float m   = (g > 0) ? -aP : 0.f;  // c<LAG <=> g==0: lag term killed

    // positional bias (s>>5 == c>>1, constant over the chunk)
    const int d0 = dg * 4;
    const int q  = c >> 1;
    const f32x4 pf = reinterpret_cast<const f32x4*>(pos_fwd)[dg];
    f32x4 add;
    add.x = pf.x + pos_bwd[(q - (d0 + 0)) & (D - 1)];
    add.y = pf.y + pos_bwd[(q - (d0 + 1)) & (D - 1)];
    add.z = pf.z + pos_bwd[(q - (d0 + 2)) & (D - 1)];
    add.w = pf.w + pos_bwd[(q - (d0 + 3)) & (D - 1)];

    const f32x4* xg = reinterpret_cast<const f32x4*>(x) + (size_t)b * S * (D / 4) + dg;

    // ---- pass A: rolled decayed chunk sum, 16 loads ----
    f32x4 A = {0.f, 0.f, 0.f, 0.f};
    #pragma unroll
    for (int i = 0; i < CL; ++i) {
        const f32x4 v = xg[(s0 + i) * (D / 4)];
        A.x = fmaf(beta, A.x, v.x);
        A.y = fmaf(beta, A.y, v.y);
        A.z = fmaf(beta, A.z, v.z);
        A.w = fmaf(beta, A.w, v.w);
    }
    sA[c][dg ^ (g & 7)] = A;          // col swizzle by row>>3 (== g): stride-8-row
                                      // gather below hits distinct 16B slots

    // pre-issue first 4 pass-B loads: vmem stays in flight across the barrier
    f32x4 p0 = xg[(s0 + 0) * (D / 4)];
    f32x4 p1 = xg[(s0 + 1) * (D / 4)];
    f32x4 p2 = xg[(s0 + 2) * (D / 4)];
    f32x4 p3 = xg[(s0 + 3) * (D / 4)];

    asm volatile("s_waitcnt lgkmcnt(0)" ::: "memory");  // sA write visible; loads fly
    __builtin_amdgcn_s_barrier();
    __builtin_amdgcn_sched_barrier(0);

    // ---- parallel window gather: y0 = alpha * sum_{k=1..8} bCL^{k-1} A_{c-k} ----
    f32x4 h = {0.f, 0.f, 0.f, 0.f};
    #pragma unroll
    for (int k = LAG; k >= 1; --k) {
        const int idx = c - k;
        f32x4 Ak = {0.f, 0.f, 0.f, 0.f};
        if (idx >= 0) Ak = sA[idx][dg ^ ((idx >> 3) & 7)];
        h.x = fmaf(bCL, h.x, Ak.x);
        h.y = fmaf(bCL, h.y, Ak.y);
        h.z = fmaf(bCL, h.z, Ak.z);
        h.w = fmaf(bCL, h.w, Ak.w);
    }
    f32x4 y;
    y.x = alpha * h.x; y.y = alpha * h.y;
    y.z = alpha * h.z; y.w = alpha * h.w;

    // ---- pass B: emit 16 outputs, PLAIN stores; lag via lockstep shfl ----
    f32x4* og = reinterpret_cast<f32x4*>(out) + ((size_t)b * S + s0) * (D / 4) + dg;
    #pragma unroll
    for (int i = 0; i < CL; ++i) {
        const f32x4 xt = (i == 0) ? p0 : (i == 1) ? p1 : (i == 2) ? p2 : (i == 3) ? p3
                                   : xg[(s0 + i) * (D / 4)];

        f32x4 o;
        o.x = y.x + add.x; o.y = y.y + add.y;
        o.z = y.z + add.z; o.w = y.w + add.w;
        og[i * (D / 4)] = o;          // plain store: full L2 write-combining path

        f32x4 xl;                     // lane-8 (group g-1) holds x[s0-P+i] in lockstep
        xl.x = __shfl_up(xt.x, 8);
        xl.y = __shfl_up(xt.y, 8);
        xl.z = __shfl_up(xt.z, 8);
        xl.w = __shfl_up(xt.w, 8);

        y.x = fmaf(beta, y.x, fmaf(alpha, xt.x, m * xl.x));
        y.y = fmaf(beta, y.y, fmaf(alpha, xt.y, m * xl.y));
        y.z = fmaf(beta, y.z, fmaf(alpha, xt.z, m * xl.z));
        y.w = fmaf(beta, y.w, fmaf(alpha, xt.w, m * xl.w));
    }
}

extern "C" void kernel_launch(void* const* d_in, const int* in_sizes, int n_in,
                              void* d_out, int out_size, void* d_ws, size_t ws_size,
                              hipStream_t stream) {
    const float* x  = (const float*)d_in[0];
    const float* al = (const float*)d_in[1];
    const float* be = (const float*)d_in[2];
    const float* pf = (const float*)d_in[3];
    const float* pb = (const float*)d_in[4];
    const int*   ps = (const int*)d_in[5];
    float* out = (float*)d_out;

    const int B = in_sizes[0] / (S * D);   // 1024 rows, one block each -> 4 blocks/CU
    attn_pred_kernel<<<dim3(B), NTHR, 0, stream>>>(x, al, be, pf, pb, ps, out);
}